// Round 1
// 580.477 us; speedup vs baseline: 1.0369x; 1.0369x over previous
//
#include <hip/hip_runtime.h>

#define NN 100000
#define HH 512
#define GG 512
#define NPACK 1280
#define NSTRIP 40
#define SB 32768               // strip bytes: 32 cols x 512 k x 2B
#define XTROWS (NN + 128)      // pad rows so tail-block xt stores are unguarded (uniform vmcnt)

typedef unsigned short u16;
typedef __bf16 bf16x8 __attribute__((ext_vector_type(8)));
typedef unsigned short u16x8 __attribute__((ext_vector_type(8)));
typedef float f32x4 __attribute__((ext_vector_type(4)));
typedef __attribute__((address_space(1))) void gvoid_t;
typedef __attribute__((address_space(3))) void lvoid_t;

__device__ __forceinline__ u16 f2bf(float f) {
    unsigned u = __float_as_uint(f);
    unsigned r = u + 0x7FFFu + ((u >> 16) & 1u);   // RNE
    return (u16)(r >> 16);
}
__device__ __forceinline__ float bf2f(u16 b) {
    return __uint_as_float(((unsigned)b) << 16);
}

// ---------------- prep: strip-blocked + XOR-swizzled W^T bf16 ------------------
// packed col n: [0,256)=ga_g_w1 ; [256,768)=ga_n_w ; [768,1280)=g_w1
// WT layout: strip s=n>>5, nl=n&31. byte = s*SB + nl*1024 + ((ck ^ (nl&15))<<4) + k3*2
//   (ck = k>>3, k3 = k&7). Linear global_load_lds copy then lands bank-conflict-free
//   for the ds_read_b128 fragment reads (2 lanes/bank, free per m136).
__global__ void k_prep(const float* __restrict__ gw1, const float* __restrict__ gb1,
                       const float* __restrict__ gw2v,
                       const float* __restrict__ nw, const float* __restrict__ nb,
                       const float* __restrict__ aw1, const float* __restrict__ ab1,
                       const float* __restrict__ aw2, const int* __restrict__ batch,
                       u16* __restrict__ WT, float* __restrict__ bias, float* __restrict__ wvec,
                       float* __restrict__ out_emb, int* __restrict__ starts) {
    int idx = blockIdx.x * blockDim.x + threadIdx.x;
    int stride = gridDim.x * blockDim.x;
    for (int i = idx; i < NPACK * 512; i += stride) {
        int n = i >> 9, k = i & 511;
        float v;
        if (n < 256)      v = gw1[k * 256 + n];
        else if (n < 768) v = nw[k * 512 + (n - 256)];
        else              v = aw1[k * 512 + (n - 768)];
        int s = n >> 5, nl = n & 31;
        int ck = k >> 3, k3 = k & 7;
        size_t byte = (size_t)s * SB + nl * 1024 + ((size_t)(ck ^ (nl & 15)) << 4) + k3 * 2;
        *(u16*)((char*)WT + byte) = f2bf(v);
    }
    for (int n = idx; n < NPACK; n += stride) {
        float bi, wv;
        if (n < 256)      { bi = gb1[n];       wv = gw2v[n]; }
        else if (n < 768) { bi = nb[n - 256];  wv = 0.f; }
        else {
            bi = ab1[n - 768];
            float s = 0.f;
            for (int h = 0; h < 8; ++h) s += aw2[(n - 768) * 8 + h];
            wv = s * 0.125f;
        }
        bias[n] = bi; wvec[n] = wv;
    }
    for (int i = idx; i < GG * HH; i += stride) out_emb[i] = 0.f;
    for (int g = idx; g <= GG; g += stride) {
        if (g == GG) { starts[GG] = NN; continue; }
        int lo = 0, hi = NN;
        while (lo < hi) { int mid = (lo + hi) >> 1; if (batch[mid] < g) lo = mid + 1; else hi = mid; }
        starts[g] = lo;
    }
}

// ---------------- fused GEMM, strip-pipelined ----------------------------------
// block = 128 rows (2 waves x 64 rows, i=4), all 1280 cols as 40 strips of 32.
// Per strip: double-buffered 32KB LDS stage (16 global_load_lds/thread), raw
// s_barrier + COUNTED vmcnt (prefetch stays in flight across barrier), 128 MFMA/wave.
// nt 0-7: gate score | nt 8-23: xt store (j-packed ushort2) | nt 24-39: att score.
__global__ __launch_bounds__(128, 1)
void k_gemm(const float* __restrict__ X, const u16* __restrict__ B,
            const float* __restrict__ bias, const float* __restrict__ wvec,
            const float* __restrict__ gb2, const float* __restrict__ ab2,
            u16* __restrict__ xt, float* __restrict__ gs, float* __restrict__ as_) {
    __shared__ __align__(16) char ldsB[2 * SB];

    const int tid = threadIdx.x;
    const int lane = tid & 63;
    const int w = tid >> 6;                  // wave -> rows [w*64, w*64+64)
    const int m0 = blockIdx.x * 128;
    const int l16 = lane & 15, kq = lane >> 4;

#define STAGE(s, bsel) do {                                                          \
    const char* _src = (const char*)B + (size_t)(s) * SB + tid * 16;                 \
    char* _dst = ldsB + (bsel) * SB + tid * 16;                                      \
    _Pragma("unroll")                                                                \
    for (int _t = 0; _t < 16; ++_t)                                                  \
        __builtin_amdgcn_global_load_lds((gvoid_t*)(_src + _t * 2048),               \
                                         (lvoid_t*)(_dst + _t * 2048), 16, 0, 0);    \
} while (0)

    STAGE(0, 0);   // strip 0 in flight under the A-panel load

    float b2 = gb2[0];
    float bb = 0.f;
#pragma unroll
    for (int h = 0; h < 8; ++h) bb += ab2[h];
    bb *= 0.125f;

    // ---- A panel: 64 rows/wave, fp32 -> bf16 fragments in registers (256 VGPR) ----
    bf16x8 a_reg[4][16];
#pragma unroll
    for (int i = 0; i < 4; ++i) {
        int row = m0 + w * 64 + i * 16 + l16;
        if (row >= NN) row = NN - 1;
        const float* xp = X + (size_t)row * 512 + kq * 8;
#pragma unroll
        for (int kt = 0; kt < 16; ++kt) {
            float4 f0 = *(const float4*)(xp + kt * 32);
            float4 f1 = *(const float4*)(xp + kt * 32 + 4);
            u16x8 u;
            u[0] = f2bf(f0.x); u[1] = f2bf(f0.y); u[2] = f2bf(f0.z); u[3] = f2bf(f0.w);
            u[4] = f2bf(f1.x); u[5] = f2bf(f1.y); u[6] = f2bf(f1.z); u[7] = f2bf(f1.w);
            a_reg[i][kt] = __builtin_bit_cast(bf16x8, u);
        }
    }

    float sg[4][4], sa[4][4];
#pragma unroll
    for (int i = 0; i < 4; ++i)
#pragma unroll
        for (int r = 0; r < 4; ++r) { sg[i][r] = 0.f; sa[i][r] = 0.f; }

    for (int nt = 0; nt < NSTRIP; ++nt) {
        const int cur = nt & 1;
        if (nt + 1 < NSTRIP) STAGE(nt + 1, cur ^ 1);
        // counted waits: need strip nt's 16 loads drained. Younger ops = 16 prefetch
        // loads (+16 ushort2 xt stores from prev epilogue when nt-1 was an xt strip).
        if (nt == NSTRIP - 1)         asm volatile("s_waitcnt vmcnt(0)" ::: "memory");
        else if (nt >= 9 && nt <= 24) asm volatile("s_waitcnt vmcnt(32)" ::: "memory");
        else                          asm volatile("s_waitcnt vmcnt(16)" ::: "memory");
        __builtin_amdgcn_s_barrier();

        f32x4 acc[4][2];
#pragma unroll
        for (int i = 0; i < 4; ++i) { acc[i][0] = {0.f,0.f,0.f,0.f}; acc[i][1] = {0.f,0.f,0.f,0.f}; }

        // b-frag: n = j*16+l16, k-chunk ck = kt*4+kq, byte = n*1024 + ((ck^l16)<<4)
        const char* bbase = ldsB + cur * SB + l16 * 1024;
#pragma unroll
        for (int kt = 0; kt < 16; ++kt) {
            int off = ((kt * 4 + kq) ^ l16) << 4;
            bf16x8 b0 = *(const bf16x8*)(bbase + off);
            bf16x8 b1 = *(const bf16x8*)(bbase + 16384 + off);
#pragma unroll
            for (int i = 0; i < 4; ++i) {
                acc[i][0] = __builtin_amdgcn_mfma_f32_16x16x32_bf16(a_reg[i][kt], b0, acc[i][0], 0, 0, 0);
                acc[i][1] = __builtin_amdgcn_mfma_f32_16x16x32_bf16(a_reg[i][kt], b1, acc[i][1], 0, 0, 0);
            }
        }
        __builtin_amdgcn_s_barrier();   // all waves done reading buf[cur] before it is restaged

        // ---- epilogue. C/D: col = lane&15, row = kq*4 + reg [m89] ----
        float bi0 = bias[nt * 32 + l16], bi1 = bias[nt * 32 + 16 + l16];
        if (nt >= 8 && nt < 24) {
            const int sx = nt - 8;     // xt position p = sx*32 + l16*2 + j (k_emb remaps)
#pragma unroll
            for (int i = 0; i < 4; ++i)
#pragma unroll
                for (int r = 0; r < 4; ++r) {
                    int rg = m0 + w * 64 + i * 16 + kq * 4 + r;   // < XTROWS always
                    ushort2 st;
                    st.x = f2bf(fmaxf(acc[i][0][r] + bi0, 0.f));
                    st.y = f2bf(fmaxf(acc[i][1][r] + bi1, 0.f));
                    *(ushort2*)(xt + (size_t)rg * 512 + sx * 32 + l16 * 2) = st;
                }
        } else {
            float w0 = wvec[nt * 32 + l16], w1 = wvec[nt * 32 + 16 + l16];
            if (nt < 8) {
#pragma unroll
                for (int i = 0; i < 4; ++i)
#pragma unroll
                    for (int r = 0; r < 4; ++r)
                        sg[i][r] += fmaxf(acc[i][0][r] + bi0, 0.f) * w0
                                  + fmaxf(acc[i][1][r] + bi1, 0.f) * w1;
            } else {
#pragma unroll
                for (int i = 0; i < 4; ++i)
#pragma unroll
                    for (int r = 0; r < 4; ++r)
                        sa[i][r] += fmaxf(acc[i][0][r] + bi0, 0.f) * w0
                                  + fmaxf(acc[i][1][r] + bi1, 0.f) * w1;
            }
        }
    }
#undef STAGE

    // ---- final scores: reduce over 16 col-lanes, coalesced write, no atomics ----
#pragma unroll
    for (int i = 0; i < 4; ++i)
#pragma unroll
        for (int r = 0; r < 4; ++r) {
            float pg = sg[i][r], pa = sa[i][r];
            pg += __shfl_xor(pg, 1); pg += __shfl_xor(pg, 2);
            pg += __shfl_xor(pg, 4); pg += __shfl_xor(pg, 8);
            pa += __shfl_xor(pa, 1); pa += __shfl_xor(pa, 2);
            pa += __shfl_xor(pa, 4); pa += __shfl_xor(pa, 8);
            int rg = m0 + w * 64 + i * 16 + kq * 4 + r;
            if (l16 == 0 && rg < NN) {
                gs[rg] = pg + b2;
                as_[rg] = pa + bb;
            }
        }
}

// ---------------- per-graph segment max + exp-sum (both scores) ----------------
__global__ void k_seg(const float* __restrict__ gs, const float* __restrict__ as_,
                      const int* __restrict__ starts,
                      float* __restrict__ mg, float* __restrict__ dg,
                      float* __restrict__ ma, float* __restrict__ da) {
    int g = blockIdx.x;
    int s0 = starts[g], s1 = starts[g + 1];
    int tid = threadIdx.x, lane = tid & 63, w = tid >> 6;
    __shared__ float red[8];
    float lmg = -3.0e38f, lma = -3.0e38f;
    for (int i = s0 + tid; i < s1; i += 256) {
        lmg = fmaxf(lmg, gs[i]); lma = fmaxf(lma, as_[i]);
    }
    for (int o = 32; o; o >>= 1) {
        lmg = fmaxf(lmg, __shfl_xor(lmg, o));
        lma = fmaxf(lma, __shfl_xor(lma, o));
    }
    if (lane == 0) { red[w] = lmg; red[4 + w] = lma; }
    __syncthreads();
    float Mg = fmaxf(fmaxf(red[0], red[1]), fmaxf(red[2], red[3]));
    float Ma = fmaxf(fmaxf(red[4], red[5]), fmaxf(red[6], red[7]));
    __syncthreads();
    float sgv = 0.f, sav = 0.f;
    for (int i = s0 + tid; i < s1; i += 256) {
        sgv += expf(gs[i] - Mg); sav += expf(as_[i] - Ma);
    }
    for (int o = 32; o; o >>= 1) { sgv += __shfl_xor(sgv, o); sav += __shfl_xor(sav, o); }
    if (lane == 0) { red[w] = sgv; red[4 + w] = sav; }
    __syncthreads();
    if (tid == 0) {
        mg[g] = Mg; ma[g] = Ma;
        dg[g] = red[0] + red[1] + red[2] + red[3];
        da[g] = red[4] + red[5] + red[6] + red[7];
    }
}

// ---------------- normalize: gate weights + attention output ----------------
__global__ void k_final(const float* __restrict__ gs, const float* __restrict__ as_,
                        const int* __restrict__ batch,
                        const float* __restrict__ mg, const float* __restrict__ dg,
                        const float* __restrict__ ma, const float* __restrict__ da,
                        float* __restrict__ gate, float* __restrict__ attn) {
    int stride = gridDim.x * blockDim.x;
    for (int i = blockIdx.x * blockDim.x + threadIdx.x; i < NN; i += stride) {
        int b = batch[i];
        gate[i] = expf(gs[i] - mg[b]) / (dg[b] + 1e-16f);
        attn[i] = expf(as_[i] - ma[b]) / (da[b] + 1e-16f);
    }
}

// ---------------- graph embedding: segment-weighted sum of xt ----------------
// xt position p maps to actual col: s=p>>5, j=p&1, l16=(p>>1)&15 -> col = s*32+j*16+l16
__global__ void k_emb(const u16* __restrict__ xt, const float* __restrict__ gate,
                      const int* __restrict__ starts, float* __restrict__ out) {
    int g = blockIdx.y;
    int part = blockIdx.x;
    int s0 = starts[g], s1 = starts[g + 1];
    int len = s1 - s0;
    int p0 = s0 + (len * part) / 4, p1 = s0 + (len * (part + 1)) / 4;
    int c2 = threadIdx.x;
    int col0 = (c2 >> 4) * 32 + (c2 & 15);   // ushort2 -> (j=0, j=1) cols col0, col0+16
    float a0 = 0.f, a1 = 0.f;
    for (int n = p0; n < p1; ++n) {
        float gn = gate[n];
        ushort2 u = reinterpret_cast<const ushort2*>(xt + (size_t)n * 512)[c2];
        a0 += gn * bf2f(u.x);
        a1 += gn * bf2f(u.y);
    }
    atomicAdd(&out[g * 512 + col0], a0);
    atomicAdd(&out[g * 512 + col0 + 16], a1);
}

extern "C" void kernel_launch(void* const* d_in, const int* in_sizes, int n_in,
                              void* d_out, int out_size, void* d_ws, size_t ws_size,
                              hipStream_t stream) {
    const float* x       = (const float*)d_in[0];
    const int*   batch   = (const int*)d_in[1];
    const float* ga_g_w1 = (const float*)d_in[2];
    const float* ga_g_b1 = (const float*)d_in[3];
    const float* ga_g_w2 = (const float*)d_in[4];
    const float* ga_g_b2 = (const float*)d_in[5];
    const float* ga_n_w  = (const float*)d_in[6];
    const float* ga_n_b  = (const float*)d_in[7];
    const float* g_w1    = (const float*)d_in[8];
    const float* g_b1    = (const float*)d_in[9];
    const float* g_w2    = (const float*)d_in[10];
    const float* g_b2    = (const float*)d_in[11];

    float* out_emb = (float*)d_out;                  // (512, 512)
    float* out_att = out_emb + GG * HH;              // (100000,)

    char* p = (char*)d_ws;
    size_t off = 0;
    auto alloc = [&](size_t bytes) -> char* {
        char* q = p + off;
        off += (bytes + 255) & ~(size_t)255;
        return q;
    };
    u16*   xt    = (u16*)  alloc((size_t)XTROWS * HH * 2);  // relu(x@ga_n_w+b) bf16 (padded)
    u16*   WT    = (u16*)  alloc((size_t)NPACK * 512 * 2);  // strip-blocked swizzled W^T bf16
    float* bias  = (float*)alloc(NPACK * 4);
    float* wvec  = (float*)alloc(NPACK * 4);
    float* gs    = (float*)alloc((size_t)NN * 4);
    float* as_   = (float*)alloc((size_t)NN * 4);
    float* gate  = (float*)alloc((size_t)NN * 4);
    float* mg    = (float*)alloc(GG * 4);
    float* dg    = (float*)alloc(GG * 4);
    float* ma    = (float*)alloc(GG * 4);
    float* da    = (float*)alloc(GG * 4);
    int*   starts= (int*)  alloc((GG + 1) * 4);

    k_prep<<<2560, 256, 0, stream>>>(ga_g_w1, ga_g_b1, ga_g_w2, ga_n_w, ga_n_b,
                                     g_w1, g_b1, g_w2, batch, WT, bias, wvec, out_emb, starts);
    k_gemm<<<782, 128, 0, stream>>>(x, WT, bias, wvec, ga_g_b2, g_b2, xt, gs, as_);
    k_seg<<<GG, 256, 0, stream>>>(gs, as_, starts, mg, dg, ma, da);
    k_final<<<400, 256, 0, stream>>>(gs, as_, batch, mg, dg, ma, da, gate, out_att);
    k_emb<<<dim3(4, GG), 256, 0, stream>>>(xt, gate, starts, out_emb);
}

// Round 2
// 469.671 us; speedup vs baseline: 1.2815x; 1.2359x over previous
//
#include <hip/hip_runtime.h>

#define NN 100000
#define HH 512
#define GG 512
#define NPACK 1280
#define NSTRIP 40
#define SB 32768               // strip bytes: 32 cols x 512 k x 2B
#define XTROWS (NN + 128)      // pad rows so tail-block xt stores are unguarded (uniform vmcnt)

typedef unsigned short u16;
typedef __bf16 bf16x8 __attribute__((ext_vector_type(8)));
typedef unsigned short u16x8 __attribute__((ext_vector_type(8)));
typedef float f32x4 __attribute__((ext_vector_type(4)));
typedef __attribute__((address_space(1))) void gvoid_t;
typedef __attribute__((address_space(3))) void lvoid_t;

__device__ __forceinline__ u16 f2bf(float f) {
    unsigned u = __float_as_uint(f);
    unsigned r = u + 0x7FFFu + ((u >> 16) & 1u);   // RNE
    return (u16)(r >> 16);
}
__device__ __forceinline__ float bf2f(u16 b) {
    return __uint_as_float(((unsigned)b) << 16);
}

// ---------------- prep: strip-blocked + XOR-swizzled W^T bf16 ------------------
// packed col n: [0,256)=ga_g_w1 ; [256,768)=ga_n_w ; [768,1280)=g_w1
// WT layout: strip s=n>>5, nl=n&31. byte = s*SB + nl*1024 + ((ck ^ (nl&15))<<4) + k3*2
//   (ck = k>>3, k3 = k&7). Linear global_load_lds copy then lands bank-conflict-free
//   for the ds_read_b128 fragment reads (2 lanes/bank, free per m136).
// bwv[n] = (bias[n], wvec[n]) packed float2 so the GEMM epilogue needs ONE stream.
__global__ void k_prep(const float* __restrict__ gw1, const float* __restrict__ gb1,
                       const float* __restrict__ gw2v,
                       const float* __restrict__ nw, const float* __restrict__ nb,
                       const float* __restrict__ aw1, const float* __restrict__ ab1,
                       const float* __restrict__ aw2, const int* __restrict__ batch,
                       u16* __restrict__ WT, float2* __restrict__ bwv,
                       float* __restrict__ out_emb, int* __restrict__ starts) {
    int idx = blockIdx.x * blockDim.x + threadIdx.x;
    int stride = gridDim.x * blockDim.x;
    for (int i = idx; i < NPACK * 512; i += stride) {
        int n = i >> 9, k = i & 511;
        float v;
        if (n < 256)      v = gw1[k * 256 + n];
        else if (n < 768) v = nw[k * 512 + (n - 256)];
        else              v = aw1[k * 512 + (n - 768)];
        int s = n >> 5, nl = n & 31;
        int ck = k >> 3, k3 = k & 7;
        size_t byte = (size_t)s * SB + nl * 1024 + ((size_t)(ck ^ (nl & 15)) << 4) + k3 * 2;
        *(u16*)((char*)WT + byte) = f2bf(v);
    }
    for (int n = idx; n < NPACK; n += stride) {
        float bi, wv;
        if (n < 256)      { bi = gb1[n];       wv = gw2v[n]; }
        else if (n < 768) { bi = nb[n - 256];  wv = 0.f; }
        else {
            bi = ab1[n - 768];
            float s = 0.f;
            for (int h = 0; h < 8; ++h) s += aw2[(n - 768) * 8 + h];
            wv = s * 0.125f;
        }
        bwv[n] = make_float2(bi, wv);
    }
    for (int i = idx; i < GG * HH; i += stride) out_emb[i] = 0.f;
    for (int g = idx; g <= GG; g += stride) {
        if (g == GG) { starts[GG] = NN; continue; }
        int lo = 0, hi = NN;
        while (lo < hi) { int mid = (lo + hi) >> 1; if (batch[mid] < g) lo = mid + 1; else hi = mid; }
        starts[g] = lo;
    }
}

// ---------------- fused GEMM, strip-pipelined ----------------------------------
// block = 128 rows as 4 waves x 32 rows (i=2 -> a_reg 128 VGPR, ~190 total, NO SPILL,
// 2 waves/SIMD for latency hiding). All 1280 cols as 40 strips of 32.
// Per strip: dbuf 32KB LDS stage (8 global_load_lds/thread), raw s_barrier + COUNTED
// vmcnt (prefetch in flight across barrier). ONLY VMEM in loop: STAGE + bwv + xt stores.
// nt 0-7: gate score | nt 8-23: xt store (j-packed ushort2) | nt 24-39: att score.
__global__ __launch_bounds__(256, 2)
void k_gemm(const float* __restrict__ X, const u16* __restrict__ B,
            const float2* __restrict__ bwv,
            const float* __restrict__ gb2, const float* __restrict__ ab2,
            u16* __restrict__ xt, float* __restrict__ gs, float* __restrict__ as_) {
    __shared__ __align__(16) char ldsB[2 * SB];

    const int tid = threadIdx.x;
    const int lane = tid & 63;
    const int w = tid >> 6;                  // wave -> rows [w*32, w*32+32)
    const int m0 = blockIdx.x * 128;
    const int l16 = lane & 15, kq = lane >> 4;

#define STAGE(s, bsel) do {                                                          \
    const char* _src = (const char*)B + (size_t)(s) * SB + tid * 16;                 \
    char* _dst = ldsB + (bsel) * SB + tid * 16;                                      \
    _Pragma("unroll")                                                                \
    for (int _t = 0; _t < 8; ++_t)                                                   \
        __builtin_amdgcn_global_load_lds((gvoid_t*)(_src + _t * 4096),               \
                                         (lvoid_t*)(_dst + _t * 4096), 16, 0, 0);    \
} while (0)

    STAGE(0, 0);   // strip 0 in flight under the A-panel load

    float b2 = gb2[0];
    float bb = 0.f;
#pragma unroll
    for (int h = 0; h < 8; ++h) bb += ab2[h];
    bb *= 0.125f;

    // ---- A panel: 32 rows/wave, fp32 -> bf16 fragments in registers (128 VGPR) ----
    bf16x8 a_reg[2][16];
#pragma unroll
    for (int i = 0; i < 2; ++i) {
        int row = m0 + w * 32 + i * 16 + l16;
        if (row >= NN) row = NN - 1;
        const float* xp = X + (size_t)row * 512 + kq * 8;
#pragma unroll
        for (int kt = 0; kt < 16; ++kt) {
            float4 f0 = *(const float4*)(xp + kt * 32);
            float4 f1 = *(const float4*)(xp + kt * 32 + 4);
            u16x8 u;
            u[0] = f2bf(f0.x); u[1] = f2bf(f0.y); u[2] = f2bf(f0.z); u[3] = f2bf(f0.w);
            u[4] = f2bf(f1.x); u[5] = f2bf(f1.y); u[6] = f2bf(f1.z); u[7] = f2bf(f1.w);
            a_reg[i][kt] = __builtin_bit_cast(bf16x8, u);
        }
    }

    float sg[2][4], sa[2][4];
#pragma unroll
    for (int i = 0; i < 2; ++i)
#pragma unroll
        for (int r = 0; r < 4; ++r) { sg[i][r] = 0.f; sa[i][r] = 0.f; }

    for (int nt = 0; nt < NSTRIP; ++nt) {
        const int cur = nt & 1;

        // bias/wvec for THIS strip: issued before the counted wait, so our own
        // vmcnt drains them -- the compiler's wait at their use is then a no-op.
        float2 bw0 = bwv[nt * 32 + l16];
        float2 bw1 = bwv[nt * 32 + 16 + l16];

        if (nt + 1 < NSTRIP) STAGE(nt + 1, cur ^ 1);

        // Counted waits (outstanding, oldest->newest: strip-nt loads 8, [xt stores 8
        // if nt-1 stored], bwv 2, prefetch 8). Drain strip-nt + bwv, keep the rest.
        if (nt == NSTRIP - 1)         asm volatile("s_waitcnt vmcnt(0)" ::: "memory");
        else if (nt >= 9 && nt <= 24) asm volatile("s_waitcnt vmcnt(18)" ::: "memory");
        else                          asm volatile("s_waitcnt vmcnt(10)" ::: "memory");
        __builtin_amdgcn_s_barrier();
        __builtin_amdgcn_sched_barrier(0);   // rule #18: no ds_read may hoist above this

        f32x4 acc[2][2];
#pragma unroll
        for (int i = 0; i < 2; ++i) { acc[i][0] = {0.f,0.f,0.f,0.f}; acc[i][1] = {0.f,0.f,0.f,0.f}; }

        // b-frag: n = j*16+l16, k-chunk ck = kt*4+kq, byte = n*1024 + ((ck^l16)<<4)
        const char* bbase = ldsB + cur * SB + l16 * 1024;
#pragma unroll
        for (int kt = 0; kt < 16; ++kt) {
            int off = ((kt * 4 + kq) ^ l16) << 4;
            bf16x8 b0 = *(const bf16x8*)(bbase + off);
            bf16x8 b1 = *(const bf16x8*)(bbase + 16384 + off);
#pragma unroll
            for (int i = 0; i < 2; ++i) {
                acc[i][0] = __builtin_amdgcn_mfma_f32_16x16x32_bf16(a_reg[i][kt], b0, acc[i][0], 0, 0, 0);
                acc[i][1] = __builtin_amdgcn_mfma_f32_16x16x32_bf16(a_reg[i][kt], b1, acc[i][1], 0, 0, 0);
            }
        }
        __builtin_amdgcn_s_barrier();   // all waves done reading buf[cur] before it is restaged

        // ---- epilogue. C/D: col = lane&15, row = kq*4 + reg [m89] ----
        if (nt >= 8 && nt < 24) {
            const int sx = nt - 8;     // xt position p = sx*32 + l16*2 + j (k_emb remaps)
#pragma unroll
            for (int i = 0; i < 2; ++i)
#pragma unroll
                for (int r = 0; r < 4; ++r) {
                    int rg = m0 + w * 32 + i * 16 + kq * 4 + r;   // < XTROWS always
                    ushort2 st;
                    st.x = f2bf(fmaxf(acc[i][0][r] + bw0.x, 0.f));
                    st.y = f2bf(fmaxf(acc[i][1][r] + bw1.x, 0.f));
                    *(ushort2*)(xt + (size_t)rg * 512 + sx * 32 + l16 * 2) = st;
                }
        } else if (nt < 8) {
#pragma unroll
            for (int i = 0; i < 2; ++i)
#pragma unroll
                for (int r = 0; r < 4; ++r)
                    sg[i][r] += fmaxf(acc[i][0][r] + bw0.x, 0.f) * bw0.y
                              + fmaxf(acc[i][1][r] + bw1.x, 0.f) * bw1.y;
        } else {
#pragma unroll
            for (int i = 0; i < 2; ++i)
#pragma unroll
                for (int r = 0; r < 4; ++r)
                    sa[i][r] += fmaxf(acc[i][0][r] + bw0.x, 0.f) * bw0.y
                              + fmaxf(acc[i][1][r] + bw1.x, 0.f) * bw1.y;
        }
    }
#undef STAGE

    // ---- final scores: reduce over 16 col-lanes, coalesced write, no atomics ----
#pragma unroll
    for (int i = 0; i < 2; ++i)
#pragma unroll
        for (int r = 0; r < 4; ++r) {
            float pg = sg[i][r], pa = sa[i][r];
            pg += __shfl_xor(pg, 1); pg += __shfl_xor(pg, 2);
            pg += __shfl_xor(pg, 4); pg += __shfl_xor(pg, 8);
            pa += __shfl_xor(pa, 1); pa += __shfl_xor(pa, 2);
            pa += __shfl_xor(pa, 4); pa += __shfl_xor(pa, 8);
            int rg = m0 + w * 32 + i * 16 + kq * 4 + r;
            if (l16 == 0 && rg < NN) {
                gs[rg] = pg + b2;
                as_[rg] = pa + bb;
            }
        }
}

// ---------------- per-graph segment max + exp-sum (both scores) ----------------
__global__ void k_seg(const float* __restrict__ gs, const float* __restrict__ as_,
                      const int* __restrict__ starts,
                      float* __restrict__ mg, float* __restrict__ dg,
                      float* __restrict__ ma, float* __restrict__ da) {
    int g = blockIdx.x;
    int s0 = starts[g], s1 = starts[g + 1];
    int tid = threadIdx.x, lane = tid & 63, w = tid >> 6;
    __shared__ float red[8];
    float lmg = -3.0e38f, lma = -3.0e38f;
    for (int i = s0 + tid; i < s1; i += 256) {
        lmg = fmaxf(lmg, gs[i]); lma = fmaxf(lma, as_[i]);
    }
    for (int o = 32; o; o >>= 1) {
        lmg = fmaxf(lmg, __shfl_xor(lmg, o));
        lma = fmaxf(lma, __shfl_xor(lma, o));
    }
    if (lane == 0) { red[w] = lmg; red[4 + w] = lma; }
    __syncthreads();
    float Mg = fmaxf(fmaxf(red[0], red[1]), fmaxf(red[2], red[3]));
    float Ma = fmaxf(fmaxf(red[4], red[5]), fmaxf(red[6], red[7]));
    __syncthreads();
    float sgv = 0.f, sav = 0.f;
    for (int i = s0 + tid; i < s1; i += 256) {
        sgv += expf(gs[i] - Mg); sav += expf(as_[i] - Ma);
    }
    for (int o = 32; o; o >>= 1) { sgv += __shfl_xor(sgv, o); sav += __shfl_xor(sav, o); }
    if (lane == 0) { red[w] = sgv; red[4 + w] = sav; }
    __syncthreads();
    if (tid == 0) {
        mg[g] = Mg; ma[g] = Ma;
        dg[g] = red[0] + red[1] + red[2] + red[3];
        da[g] = red[4] + red[5] + red[6] + red[7];
    }
}

// ---------------- normalize: gate weights + attention output ----------------
__global__ void k_final(const float* __restrict__ gs, const float* __restrict__ as_,
                        const int* __restrict__ batch,
                        const float* __restrict__ mg, const float* __restrict__ dg,
                        const float* __restrict__ ma, const float* __restrict__ da,
                        float* __restrict__ gate, float* __restrict__ attn) {
    int stride = gridDim.x * blockDim.x;
    for (int i = blockIdx.x * blockDim.x + threadIdx.x; i < NN; i += stride) {
        int b = batch[i];
        gate[i] = expf(gs[i] - mg[b]) / (dg[b] + 1e-16f);
        attn[i] = expf(as_[i] - ma[b]) / (da[b] + 1e-16f);
    }
}

// ---------------- graph embedding: segment-weighted sum of xt ----------------
// xt position p maps to actual col: s=p>>5, j=p&1, l16=(p>>1)&15 -> col = s*32+j*16+l16
__global__ void k_emb(const u16* __restrict__ xt, const float* __restrict__ gate,
                      const int* __restrict__ starts, float* __restrict__ out) {
    int g = blockIdx.y;
    int part = blockIdx.x;
    int s0 = starts[g], s1 = starts[g + 1];
    int len = s1 - s0;
    int p0 = s0 + (len * part) / 4, p1 = s0 + (len * (part + 1)) / 4;
    int c2 = threadIdx.x;
    int col0 = (c2 >> 4) * 32 + (c2 & 15);   // ushort2 -> (j=0, j=1) cols col0, col0+16
    float a0 = 0.f, a1 = 0.f;
    for (int n = p0; n < p1; ++n) {
        float gn = gate[n];
        ushort2 u = reinterpret_cast<const ushort2*>(xt + (size_t)n * 512)[c2];
        a0 += gn * bf2f(u.x);
        a1 += gn * bf2f(u.y);
    }
    atomicAdd(&out[g * 512 + col0], a0);
    atomicAdd(&out[g * 512 + col0 + 16], a1);
}

extern "C" void kernel_launch(void* const* d_in, const int* in_sizes, int n_in,
                              void* d_out, int out_size, void* d_ws, size_t ws_size,
                              hipStream_t stream) {
    const float* x       = (const float*)d_in[0];
    const int*   batch   = (const int*)d_in[1];
    const float* ga_g_w1 = (const float*)d_in[2];
    const float* ga_g_b1 = (const float*)d_in[3];
    const float* ga_g_w2 = (const float*)d_in[4];
    const float* ga_g_b2 = (const float*)d_in[5];
    const float* ga_n_w  = (const float*)d_in[6];
    const float* ga_n_b  = (const float*)d_in[7];
    const float* g_w1    = (const float*)d_in[8];
    const float* g_b1    = (const float*)d_in[9];
    const float* g_w2    = (const float*)d_in[10];
    const float* g_b2    = (const float*)d_in[11];

    float* out_emb = (float*)d_out;                  // (512, 512)
    float* out_att = out_emb + GG * HH;              // (100000,)

    char* p = (char*)d_ws;
    size_t off = 0;
    auto alloc = [&](size_t bytes) -> char* {
        char* q = p + off;
        off += (bytes + 255) & ~(size_t)255;
        return q;
    };
    u16*    xt    = (u16*)   alloc((size_t)XTROWS * HH * 2);  // relu(x@ga_n_w+b) bf16 (padded)
    u16*    WT    = (u16*)   alloc((size_t)NPACK * 512 * 2);  // strip-blocked swizzled W^T bf16
    float2* bwv   = (float2*)alloc(NPACK * 8);                // (bias, wvec) pairs
    float*  gs    = (float*) alloc((size_t)NN * 4);
    float*  as_   = (float*) alloc((size_t)NN * 4);
    float*  gate  = (float*) alloc((size_t)NN * 4);
    float*  mg    = (float*) alloc(GG * 4);
    float*  dg    = (float*) alloc(GG * 4);
    float*  ma    = (float*) alloc(GG * 4);
    float*  da    = (float*) alloc(GG * 4);
    int*    starts= (int*)   alloc((GG + 1) * 4);

    k_prep<<<2560, 256, 0, stream>>>(ga_g_w1, ga_g_b1, ga_g_w2, ga_n_w, ga_n_b,
                                     g_w1, g_b1, g_w2, batch, WT, bwv, out_emb, starts);
    k_gemm<<<782, 256, 0, stream>>>(x, WT, bwv, ga_g_b2, g_b2, xt, gs, as_);
    k_seg<<<GG, 256, 0, stream>>>(gs, as_, starts, mg, dg, ma, da);
    k_final<<<400, 256, 0, stream>>>(gs, as_, batch, mg, dg, ma, da, gate, out_att);
    k_emb<<<dim3(4, GG), 256, 0, stream>>>(xt, gate, starts, out_emb);
}